// Round 2
// baseline (442.555 us; speedup 1.0000x reference)
//
#include <hip/hip_runtime.h>

#define B_ 8
#define T_ 16
#define D_ 1536
#define N_ 12
#define KH_ 2
#define G_ 6
#define H_ 128
#define S_ 8192
#define NCHUNK 16

typedef __attribute__((ext_vector_type(8))) short bf16x8;
typedef __attribute__((ext_vector_type(4))) float f32x4;
typedef __attribute__((ext_vector_type(4))) unsigned short u16x4;

__device__ __forceinline__ unsigned short f2bf(float x) {
    unsigned u = __float_as_uint(x);
    u += 0x7fffu + ((u >> 16) & 1u);
    return (unsigned short)(u >> 16);
}
__device__ __forceinline__ float bf2f(unsigned short h) {
    return __uint_as_float(((unsigned)h) << 16);
}

// ---------------------------------------------------------------------------
// MFMA split-bf16 GEMM: C(128 x N) = A(128 x Kdim) * B(Kdim x N)
// A row-major with lda == Kdim. B row-major with ldb. 64x64 tile per block.
// grid = (N/64, 2). 256 threads = 4 waves, wave w owns rows w*16..+15.
// Split-bf16: A ~ Ah+Al, B ~ Bh+Bl; C ≈ Ah*Bh + Ah*Bl + Al*Bh (f32 acc).
// ---------------------------------------------------------------------------
__global__ __launch_bounds__(256, 2) void gemm128_mfma(
    const float* __restrict__ A, const float* __restrict__ B,
    float* __restrict__ C, int ldb, int ldc, int Kdim)
{
    __shared__ __align__(16) unsigned short Ah[64][40], Al[64][40];
    __shared__ __align__(16) unsigned short Bh[64][40], Bl[64][40];
    const int tid = threadIdx.x;
    const int wave = tid >> 6, lane = tid & 63;
    const int col = lane & 15, g = lane >> 4;
    const int row0 = blockIdx.y * 64, col0 = blockIdx.x * 64;

    f32x4 acc[4];
#pragma unroll
    for (int nt = 0; nt < 4; ++nt) acc[nt] = (f32x4){0.f, 0.f, 0.f, 0.f};

    for (int kk = 0; kk < Kdim; kk += 32) {
        __syncthreads();
        // stage A: 64 rows x 32 k  (512 float4 chunks)
        for (int c = tid; c < 512; c += 256) {
            int r = c >> 3, k4 = c & 7;
            float4 v = *(const float4*)&A[(size_t)(row0 + r) * Kdim + kk + k4 * 4];
            float f[4] = {v.x, v.y, v.z, v.w};
            u16x4 hv, lv;
#pragma unroll
            for (int i = 0; i < 4; ++i) {
                unsigned short hh = f2bf(f[i]);
                hv[i] = hh; lv[i] = f2bf(f[i] - bf2f(hh));
            }
            *(u16x4*)&Ah[r][k4 * 4] = hv;
            *(u16x4*)&Al[r][k4 * 4] = lv;
        }
        // stage B transposed: Bt[col][k], 4x4 chunks
        if (tid < 128) {
            int kq = tid >> 4, cq = tid & 15;
            float a[4][4];
#pragma unroll
            for (int r = 0; r < 4; ++r) {
                float4 v = *(const float4*)&B[(size_t)(kk + kq * 4 + r) * ldb + col0 + cq * 4];
                a[r][0] = v.x; a[r][1] = v.y; a[r][2] = v.z; a[r][3] = v.w;
            }
#pragma unroll
            for (int cc = 0; cc < 4; ++cc) {
                u16x4 hv, lv;
#pragma unroll
                for (int r = 0; r < 4; ++r) {
                    unsigned short hh = f2bf(a[r][cc]);
                    hv[r] = hh; lv[r] = f2bf(a[r][cc] - bf2f(hh));
                }
                *(u16x4*)&Bh[cq * 4 + cc][kq * 4] = hv;
                *(u16x4*)&Bl[cq * 4 + cc][kq * 4] = lv;
            }
        }
        __syncthreads();

        bf16x8 ah = *(const bf16x8*)&Ah[wave * 16 + col][g * 8];
        bf16x8 al = *(const bf16x8*)&Al[wave * 16 + col][g * 8];
#pragma unroll
        for (int nt = 0; nt < 4; ++nt) {
            bf16x8 bh = *(const bf16x8*)&Bh[nt * 16 + col][g * 8];
            bf16x8 bl = *(const bf16x8*)&Bl[nt * 16 + col][g * 8];
            acc[nt] = __builtin_amdgcn_mfma_f32_16x16x32_bf16(ah, bh, acc[nt], 0, 0, 0);
            acc[nt] = __builtin_amdgcn_mfma_f32_16x16x32_bf16(ah, bl, acc[nt], 0, 0, 0);
            acc[nt] = __builtin_amdgcn_mfma_f32_16x16x32_bf16(al, bh, acc[nt], 0, 0, 0);
        }
    }
#pragma unroll
    for (int nt = 0; nt < 4; ++nt)
#pragma unroll
        for (int j = 0; j < 4; ++j)
            C[(size_t)(row0 + wave * 16 + g * 4 + j) * ldc + col0 + nt * 16 + col] = acc[nt][j];
}

// ---------------------------------------------------------------------------
// Bias add + RoPE. One block per (b,t) row.
// ---------------------------------------------------------------------------
__global__ __launch_bounds__(128) void rope_kernel(
    const float* __restrict__ q_acc, const float* __restrict__ k_acc,
    const float* __restrict__ v_acc,
    const float* __restrict__ bq, const float* __restrict__ bk,
    const float* __restrict__ bv,
    const int* __restrict__ seg, const int* __restrict__ start_ind,
    const int* __restrict__ curp,
    float* __restrict__ q_rope, float* __restrict__ k_new,
    float* __restrict__ v_new)
{
    const int row = blockIdx.x;
    const int b = row >> 4, t = row & 15;
    const int tid = threadIdx.x;
    __shared__ float sc[64][2];

    const int CUR = curp[0];
    int c = 0;
    for (int tt = 0; tt <= t; ++tt) c += (seg[b * T_ + tt] != 0) ? 1 : 0;
    int pos = max(c - 1, 0) + CUR;

    if (tid < 64) {
        float frac = (2.0f * tid) / (float)H_;
        float ts = expf(frac * logf(1000000.0f));
        float ang = (float)pos / ts;
        sc[tid][0] = sinf(ang);
        sc[tid][1] = cosf(ang);
    }
    __syncthreads();

    for (int e = tid; e < N_ * 64; e += 128) {
        int n = e >> 6, i = e & 63;
        size_t base = (size_t)row * (N_ * H_) + n * H_;
        float x1 = q_acc[base + i] + bq[n * H_ + i];
        float x2 = q_acc[base + i + 64] + bq[n * H_ + i + 64];
        float s = sc[i][0], co = sc[i][1];
        q_rope[base + i]      = x1 * co - x2 * s;
        q_rope[base + i + 64] = x2 * co + x1 * s;
    }
    for (int e = tid; e < KH_ * 64; e += 128) {
        int n = e >> 6, i = e & 63;
        size_t base = (size_t)row * (KH_ * H_) + n * H_;
        float x1 = k_acc[base + i] + bk[n * H_ + i];
        float x2 = k_acc[base + i + 64] + bk[n * H_ + i + 64];
        float s = sc[i][0], co = sc[i][1];
        k_new[base + i]      = x1 * co - x2 * s;
        k_new[base + i + 64] = x2 * co + x1 * s;
    }
    for (int e = tid; e < KH_ * H_; e += 128)
        v_new[(size_t)row * (KH_ * H_) + e] =
            v_acc[(size_t)row * (KH_ * H_) + e] + bv[e];
}

// ---------------------------------------------------------------------------
// MFMA flash attention, split-KV. grid = (NCHUNK, B, KH), 384 thr = 6 waves.
// Wave w owns 16 queries (qi = w*16..+15, qi = t*G+g). KV tiles of 32 keys.
// QK: S(16x32) = Q(16x128) * K^T; online softmax on C-layout rows;
// P -> per-wave LDS (bf16 hi/lo) -> A-frag; PV: O(16x128) += P(16x32)*V.
// Partials per chunk: [chunk][b][kh][qi][132] = {m, l, acc[128], pad2}
// ---------------------------------------------------------------------------
__global__ __launch_bounds__(384, 2) void attn_mfma(
    const float* __restrict__ q_rope, const float* __restrict__ k_new,
    const float* __restrict__ v_new,
    const float* __restrict__ k_cache, const float* __restrict__ v_cache,
    const int* __restrict__ seg, const int* __restrict__ start_ind,
    const int* __restrict__ curp,
    float* __restrict__ part)
{
    const int chunk = blockIdx.x, b = blockIdx.y, kh = blockIdx.z;
    const int tid = threadIdx.x;
    const int wave = tid >> 6, lane = tid & 63;
    const int col = lane & 15, g = lane >> 4;
    const float scale = 0.088388347648318447f;
    const float NEG_INF = -__builtin_inff();

    const int CUR = curp[0];
    const int SPAN = CUR + T_;
    const int CH = (SPAN + NCHUNK - 1) / NCHUNK;
    const int s0 = chunk * CH;
    const int s1 = min(s0 + CH, SPAN);

    int st = start_ind[b];
    if (st < 0) {
        st = 0;
        for (int tt = 0; tt < T_; ++tt)
            if (seg[b * T_ + tt] != 0) { st = tt; break; }
    }

    __shared__ __align__(16) unsigned short K_hi[32][136], K_lo[32][136]; // 17.0 KiB
    __shared__ __align__(16) unsigned short Vt_hi[128][40], Vt_lo[128][40]; // 20 KiB
    __shared__ __align__(16) unsigned short P_hi[6][16][40], P_lo[6][16][40]; // 15 KiB

    // ---- Q prologue: A-fragments in registers (scale folded in) ----
    const int qbase = wave * 16;
    const int qi_a = qbase + col;
    const int t_a = (qi_a * 171) >> 10;          // qi/6 for qi<96
    const int gh_a = qi_a - t_a * G_;
    const float* qp = &q_rope[(((size_t)b * T_ + t_a) * N_ + kh * G_ + gh_a) * H_];
    bf16x8 qh[4], ql[4];
#pragma unroll
    for (int ks = 0; ks < 4; ++ks) {
        float4 va = *(const float4*)&qp[ks * 32 + g * 8];
        float4 vb = *(const float4*)&qp[ks * 32 + g * 8 + 4];
        float f[8] = {va.x, va.y, va.z, va.w, vb.x, vb.y, vb.z, vb.w};
#pragma unroll
        for (int i = 0; i < 8; ++i) {
            float xs = f[i] * scale;
            unsigned short hh = f2bf(xs);
            qh[ks][i] = (short)hh;
            ql[ks][i] = (short)f2bf(xs - bf2f(hh));
        }
    }

    // per-C-row (query) metadata
    int qpos_r[4], segid_r[4];
#pragma unroll
    for (int j = 0; j < 4; ++j) {
        int qi_c = qbase + g * 4 + j;
        int t_c = (qi_c * 171) >> 10;
        segid_r[j] = seg[b * T_ + t_c];
        qpos_r[j] = CUR + t_c - st;
    }

    float m[4], lsum[4];
#pragma unroll
    for (int j = 0; j < 4; ++j) { m[j] = NEG_INF; lsum[j] = 0.f; }
    f32x4 oacc[8];
#pragma unroll
    for (int nt = 0; nt < 8; ++nt) oacc[nt] = (f32x4){0.f, 0.f, 0.f, 0.f};

    for (int stile = s0; stile < s1; stile += 32) {
        __syncthreads();
        // ---- stage K tile (natural [key][dim], hi/lo) ----
        for (int c = tid; c < 1024; c += 384) {
            int key = c >> 5, d4 = c & 31;
            int s = stile + key;
            float4 v = {0.f, 0.f, 0.f, 0.f};
            if (s < s1) {
                const float* src = (s < CUR)
                    ? &k_cache[((((size_t)b * S_ + s) * KH_) + kh) * H_ + d4 * 4]
                    : &k_new[((((size_t)b * T_ + (s - CUR)) * KH_) + kh) * H_ + d4 * 4];
                v = *(const float4*)src;
            }
            float f[4] = {v.x, v.y, v.z, v.w};
            u16x4 hv, lv;
#pragma unroll
            for (int i = 0; i < 4; ++i) {
                unsigned short hh = f2bf(f[i]);
                hv[i] = hh; lv[i] = f2bf(f[i] - bf2f(hh));
            }
            *(u16x4*)&K_hi[key][d4 * 4] = hv;
            *(u16x4*)&K_lo[key][d4 * 4] = lv;
        }
        // ---- stage V transposed (Vt[dim][key], hi/lo) ----
        if (tid < 256) {
            int ky4 = tid >> 5, d4 = tid & 31;
            float a[4][4];
#pragma unroll
            for (int r = 0; r < 4; ++r) {
                int s = stile + ky4 * 4 + r;
                float4 v = {0.f, 0.f, 0.f, 0.f};
                if (s < s1) {
                    const float* src = (s < CUR)
                        ? &v_cache[((((size_t)b * S_ + s) * KH_) + kh) * H_ + d4 * 4]
                        : &v_new[((((size_t)b * T_ + (s - CUR)) * KH_) + kh) * H_ + d4 * 4];
                    v = *(const float4*)src;
                }
                a[r][0] = v.x; a[r][1] = v.y; a[r][2] = v.z; a[r][3] = v.w;
            }
#pragma unroll
            for (int dd = 0; dd < 4; ++dd) {
                u16x4 hv, lv;
#pragma unroll
                for (int r = 0; r < 4; ++r) {
                    unsigned short hh = f2bf(a[r][dd]);
                    hv[r] = hh; lv[r] = f2bf(a[r][dd] - bf2f(hh));
                }
                *(u16x4*)&Vt_hi[d4 * 4 + dd][ky4 * 4] = hv;
                *(u16x4*)&Vt_lo[d4 * 4 + dd][ky4 * 4] = lv;
            }
        }
        __syncthreads();

        // ---- QK^T via MFMA (2 key N-tiles x 4 K-steps x 3 split products) --
        f32x4 sacc0 = {0.f, 0.f, 0.f, 0.f}, sacc1 = {0.f, 0.f, 0.f, 0.f};
#pragma unroll
        for (int ks = 0; ks < 4; ++ks) {
            bf16x8 k0h = *(const bf16x8*)&K_hi[col][ks * 32 + g * 8];
            bf16x8 k0l = *(const bf16x8*)&K_lo[col][ks * 32 + g * 8];
            bf16x8 k1h = *(const bf16x8*)&K_hi[16 + col][ks * 32 + g * 8];
            bf16x8 k1l = *(const bf16x8*)&K_lo[16 + col][ks * 32 + g * 8];
            sacc0 = __builtin_amdgcn_mfma_f32_16x16x32_bf16(qh[ks], k0h, sacc0, 0, 0, 0);
            sacc0 = __builtin_amdgcn_mfma_f32_16x16x32_bf16(qh[ks], k0l, sacc0, 0, 0, 0);
            sacc0 = __builtin_amdgcn_mfma_f32_16x16x32_bf16(ql[ks], k0h, sacc0, 0, 0, 0);
            sacc1 = __builtin_amdgcn_mfma_f32_16x16x32_bf16(qh[ks], k1h, sacc1, 0, 0, 0);
            sacc1 = __builtin_amdgcn_mfma_f32_16x16x32_bf16(qh[ks], k1l, sacc1, 0, 0, 0);
            sacc1 = __builtin_amdgcn_mfma_f32_16x16x32_bf16(ql[ks], k1h, sacc1, 0, 0, 0);
        }

        // ---- mask + online softmax (C layout: row=g*4+j, col within tile) --
        float rj[4];
        const int skey0 = stile + col, skey1 = stile + 16 + col;
#pragma unroll
        for (int j = 0; j < 4; ++j) {
            bool v0 = (skey0 < s1) && (skey0 - st <= qpos_r[j]) &&
                      (((skey0 >= st) ? 1 : 0) == segid_r[j]);
            bool v1 = (skey1 < s1) && (skey1 - st <= qpos_r[j]) &&
                      (((skey1 >= st) ? 1 : 0) == segid_r[j]);
            float lg0 = v0 ? sacc0[j] : NEG_INF;
            float lg1 = v1 ? sacc1[j] : NEG_INF;
            float tm = fmaxf(lg0, lg1);
            tm = fmaxf(tm, __shfl_xor(tm, 1));
            tm = fmaxf(tm, __shfl_xor(tm, 2));
            tm = fmaxf(tm, __shfl_xor(tm, 4));
            tm = fmaxf(tm, __shfl_xor(tm, 8));
            float mn = fmaxf(m[j], tm);
            float r, p0, p1;
            if (mn == NEG_INF) { r = 1.f; p0 = 0.f; p1 = 0.f; }
            else {
                r  = __expf(m[j] - mn);
                p0 = __expf(lg0 - mn);
                p1 = __expf(lg1 - mn);
            }
            float ps = p0 + p1;
            ps += __shfl_xor(ps, 1);
            ps += __shfl_xor(ps, 2);
            ps += __shfl_xor(ps, 4);
            ps += __shfl_xor(ps, 8);
            lsum[j] = lsum[j] * r + ps;
            m[j] = mn;
            rj[j] = r;
            int row = g * 4 + j;
            unsigned short h0 = f2bf(p0);
            P_hi[wave][row][col] = h0;
            P_lo[wave][row][col] = f2bf(p0 - bf2f(h0));
            unsigned short h1 = f2bf(p1);
            P_hi[wave][row][16 + col] = h1;
            P_lo[wave][row][16 + col] = f2bf(p1 - bf2f(h1));
        }

        // rescale O accumulator
#pragma unroll
        for (int nt = 0; nt < 8; ++nt) {
#pragma unroll
            for (int j = 0; j < 4; ++j) oacc[nt][j] *= rj[j];
        }

        // ---- PV via MFMA (A = P from per-wave LDS, B = Vt) ----
        bf16x8 pah = *(const bf16x8*)&P_hi[wave][col][g * 8];
        bf16x8 pal = *(const bf16x8*)&P_lo[wave][col][g * 8];
#pragma unroll
        for (int nt = 0; nt < 8; ++nt) {
            bf16x8 vbh = *(const bf16x8*)&Vt_hi[nt * 16 + col][g * 8];
            bf16x8 vbl = *(const bf16x8*)&Vt_lo[nt * 16 + col][g * 8];
            oacc[nt] = __builtin_amdgcn_mfma_f32_16x16x32_bf16(pah, vbh, oacc[nt], 0, 0, 0);
            oacc[nt] = __builtin_amdgcn_mfma_f32_16x16x32_bf16(pah, vbl, oacc[nt], 0, 0, 0);
            oacc[nt] = __builtin_amdgcn_mfma_f32_16x16x32_bf16(pal, vbh, oacc[nt], 0, 0, 0);
        }
    }

    // ---- write partials ----
    const size_t base_q = (((size_t)chunk * B_ + b) * KH_ + kh) * 96;
#pragma unroll
    for (int j = 0; j < 4; ++j) {
        int qi = qbase + g * 4 + j;
        size_t pb = (base_q + qi) * 132;
        if (col == 0) { part[pb] = m[j]; part[pb + 1] = lsum[j]; }
#pragma unroll
        for (int nt = 0; nt < 8; ++nt)
            part[pb + 2 + nt * 16 + col] = oacc[nt][j];
    }
}

// ---------------------------------------------------------------------------
// Combine per-chunk partials -> qkv (b,t,N,H)
// ---------------------------------------------------------------------------
__global__ __launch_bounds__(256) void combine_kernel(
    const float* __restrict__ part, float* __restrict__ qkv)
{
    const int row = blockIdx.x;
    const int b = row >> 4, t = row & 15;
    const int tid = threadIdx.x;
    const int half = tid >> 7, h = tid & 127;
    const size_t cstride = (size_t)B_ * KH_ * 96 * 132;

    for (int nb = 0; nb < N_; nb += 2) {
        int n = nb + half;
        int kh = n / G_, g = n - kh * G_;
        int qi = t * G_ + g;
        size_t base0 = (((size_t)b * KH_ + kh) * 96 + qi) * 132;
        float M = -__builtin_inff();
        for (int c = 0; c < NCHUNK; ++c)
            M = fmaxf(M, part[base0 + c * cstride]);
        float den = 0.f, num = 0.f;
        for (int c = 0; c < NCHUNK; ++c) {
            float mc = part[base0 + c * cstride];
            float e = (M == -__builtin_inff() || mc == -__builtin_inff())
                          ? 0.f : expf(mc - M);
            den += e * part[base0 + c * cstride + 1];
            num += e * part[base0 + c * cstride + 2 + h];
        }
        qkv[(size_t)row * (N_ * H_) + n * H_ + h] = (den > 0.f) ? num / den : 0.f;
    }
}

// ---------------------------------------------------------------------------
extern "C" void kernel_launch(void* const* d_in, const int* in_sizes, int n_in,
                              void* d_out, int out_size, void* d_ws, size_t ws_size,
                              hipStream_t stream)
{
    (void)in_sizes; (void)n_in; (void)out_size; (void)ws_size;
    const float* x       = (const float*)d_in[0];
    const float* k_cache = (const float*)d_in[1];
    const float* v_cache = (const float*)d_in[2];
    const float* wq      = (const float*)d_in[3];
    const float* bq      = (const float*)d_in[4];
    const float* wk      = (const float*)d_in[5];
    const float* bk      = (const float*)d_in[6];
    const float* wv      = (const float*)d_in[7];
    const float* bv      = (const float*)d_in[8];
    const float* wo      = (const float*)d_in[9];
    const int*   seg     = (const int*)d_in[10];
    const int*   start_i = (const int*)d_in[11];
    const int*   curp    = (const int*)d_in[12];
    float* out = (float*)d_out;
    float* ws  = (float*)d_ws;

    const size_t QSZ = (size_t)B_ * T_ * N_ * H_;   // 196608
    const size_t KSZ = (size_t)B_ * T_ * KH_ * H_;  // 32768
    float* q_acc  = ws;
    float* k_acc  = q_acc + QSZ;
    float* v_acc  = k_acc + KSZ;
    float* q_rope = v_acc + KSZ;
    float* k_new  = q_rope + QSZ;
    float* v_new  = k_new + KSZ;
    float* part   = v_new + KSZ;
    const size_t PSZ = (size_t)NCHUNK * B_ * KH_ * 96 * 132;
    float* qkv    = part + PSZ;

    // projections (MFMA, no atomics, no memset)
    gemm128_mfma<<<dim3(24, 2), 256, 0, stream>>>(x, wq, q_acc, N_ * H_, N_ * H_, D_);
    gemm128_mfma<<<dim3(4, 2),  256, 0, stream>>>(x, wk, k_acc, KH_ * H_, KH_ * H_, D_);
    gemm128_mfma<<<dim3(4, 2),  256, 0, stream>>>(x, wv, v_acc, KH_ * H_, KH_ * H_, D_);

    rope_kernel<<<B_ * T_, 128, 0, stream>>>(q_acc, k_acc, v_acc, bq, bk, bv,
                                             seg, start_i, curp,
                                             q_rope, k_new, v_new);

    attn_mfma<<<dim3(NCHUNK, B_, KH_), 384, 0, stream>>>(
        q_rope, k_new, v_new, k_cache, v_cache, seg, start_i, curp, part);

    combine_kernel<<<B_ * T_, 256, 0, stream>>>(part, qkv);

    gemm128_mfma<<<dim3(24, 2), 256, 0, stream>>>(qkv, wo, out, D_, D_, N_ * H_);
}

// Round 3
// 107.622 us; speedup vs baseline: 4.1121x; 4.1121x over previous
//
#include <hip/hip_runtime.h>

#define B_ 8
#define T_ 16
#define D_ 1536
#define N_ 12
#define KH_ 2
#define G_ 6
#define H_ 128
#define S_ 8192
#define NCHUNK 16
#define SPLITS 8

typedef __attribute__((ext_vector_type(8))) short bf16x8;
typedef __attribute__((ext_vector_type(4))) float f32x4;
typedef __attribute__((ext_vector_type(4))) unsigned short u16x4;

__device__ __forceinline__ unsigned short f2bf(float x) {
    unsigned u = __float_as_uint(x);
    u += 0x7fffu + ((u >> 16) & 1u);
    return (unsigned short)(u >> 16);
}
__device__ __forceinline__ float bf2f(unsigned short h) {
    return __uint_as_float(((unsigned)h) << 16);
}

// ---------------------------------------------------------------------------
// Split-K MFMA GEMM with split-bf16 (3-product) accuracy.
// C_partial[split][128][NTOT] = A(128 x Kdim) * W(Kdim x NTOT)
// W is up to 3 concatenated regions (for fused q/k/v): cols [0,n0) from W0,
// [n0,n0+n1) from W1, rest from W2. 64x64 tile per block.
// grid = (NTOT/64, 2, SPLITS), 256 threads = 4 waves.
// ---------------------------------------------------------------------------
__global__ __launch_bounds__(256, 4) void gemm_splitk(
    const float* __restrict__ A,
    const float* __restrict__ W0, int n0, int ldb0,
    const float* __restrict__ W1, int n1, int ldb1,
    const float* __restrict__ W2, int ldb2,
    float* __restrict__ part, int NTOT, int Kdim)
{
    __shared__ __align__(16) unsigned short Ah[64][40], Al[64][40];
    __shared__ __align__(16) unsigned short Bh[64][40], Bl[64][40];
    const int tid = threadIdx.x;
    const int wave = tid >> 6, lane = tid & 63;
    const int col = lane & 15, g = lane >> 4;
    const int row0 = blockIdx.y * 64;
    const int c0 = blockIdx.x * 64;
    const int ks = Kdim / gridDim.z;
    const int k0 = blockIdx.z * ks;

    const float* Bp; int ldb, bc0;
    if (c0 < n0)           { Bp = W0; ldb = ldb0; bc0 = c0; }
    else if (c0 < n0 + n1) { Bp = W1; ldb = ldb1; bc0 = c0 - n0; }
    else                   { Bp = W2; ldb = ldb2; bc0 = c0 - n0 - n1; }

    f32x4 acc[4];
#pragma unroll
    for (int nt = 0; nt < 4; ++nt) acc[nt] = (f32x4){0.f, 0.f, 0.f, 0.f};

    for (int kk = 0; kk < ks; kk += 32) {
        __syncthreads();
        if (tid < 128) {
            // stage A: 64 rows x 32 k, 4 float4 chunks per thread
#pragma unroll
            for (int c = tid; c < 512; c += 128) {
                int r = c >> 3, k4 = c & 7;
                float4 v = *(const float4*)&A[(size_t)(row0 + r) * Kdim + k0 + kk + k4 * 4];
                float f[4] = {v.x, v.y, v.z, v.w};
                u16x4 hv, lv;
#pragma unroll
                for (int i = 0; i < 4; ++i) {
                    unsigned short hh = f2bf(f[i]);
                    hv[i] = hh; lv[i] = f2bf(f[i] - bf2f(hh));
                }
                *(u16x4*)&Ah[r][k4 * 4] = hv;
                *(u16x4*)&Al[r][k4 * 4] = lv;
            }
        } else {
            // stage B transposed: Bt[col][k]
            int t2 = tid - 128;
            int kq = t2 >> 4, cq = t2 & 15;
            float a[4][4];
#pragma unroll
            for (int r = 0; r < 4; ++r) {
                float4 v = *(const float4*)&Bp[(size_t)(k0 + kk + kq * 4 + r) * ldb + bc0 + cq * 4];
                a[r][0] = v.x; a[r][1] = v.y; a[r][2] = v.z; a[r][3] = v.w;
            }
#pragma unroll
            for (int cc = 0; cc < 4; ++cc) {
                u16x4 hv, lv;
#pragma unroll
                for (int r = 0; r < 4; ++r) {
                    unsigned short hh = f2bf(a[r][cc]);
                    hv[r] = hh; lv[r] = f2bf(a[r][cc] - bf2f(hh));
                }
                *(u16x4*)&Bh[cq * 4 + cc][kq * 4] = hv;
                *(u16x4*)&Bl[cq * 4 + cc][kq * 4] = lv;
            }
        }
        __syncthreads();

        bf16x8 ah = *(const bf16x8*)&Ah[wave * 16 + col][g * 8];
        bf16x8 al = *(const bf16x8*)&Al[wave * 16 + col][g * 8];
#pragma unroll
        for (int nt = 0; nt < 4; ++nt) {
            bf16x8 bh = *(const bf16x8*)&Bh[nt * 16 + col][g * 8];
            bf16x8 bl = *(const bf16x8*)&Bl[nt * 16 + col][g * 8];
            acc[nt] = __builtin_amdgcn_mfma_f32_16x16x32_bf16(ah, bh, acc[nt], 0, 0, 0);
            acc[nt] = __builtin_amdgcn_mfma_f32_16x16x32_bf16(ah, bl, acc[nt], 0, 0, 0);
            acc[nt] = __builtin_amdgcn_mfma_f32_16x16x32_bf16(al, bh, acc[nt], 0, 0, 0);
        }
    }
#pragma unroll
    for (int nt = 0; nt < 4; ++nt)
#pragma unroll
        for (int j = 0; j < 4; ++j) {
            size_t prow = (size_t)blockIdx.z * 128 + row0 + wave * 16 + g * 4 + j;
            part[prow * NTOT + c0 + nt * 16 + col] = acc[nt][j];
        }
}

// ---------------------------------------------------------------------------
// Reduce SPLITS partials + bias + RoPE. One block per (b,t) row.
// Partial layout: [split][128][2048]; cols [0,1536)=q, [1536,1792)=k, rest v.
// ---------------------------------------------------------------------------
__global__ __launch_bounds__(256) void rope_reduce(
    const float* __restrict__ part,
    const float* __restrict__ bq, const float* __restrict__ bk,
    const float* __restrict__ bv,
    const int* __restrict__ seg, const int* __restrict__ curp,
    float* __restrict__ q_rope, float* __restrict__ k_new,
    float* __restrict__ v_new)
{
    const int row = blockIdx.x;
    const int b = row >> 4, t = row & 15;
    const int tid = threadIdx.x;
    __shared__ float S[2048];
    __shared__ float sc[64][2];

    const int CUR = curp[0];
    int c = 0;
    for (int tt = 0; tt <= t; ++tt) c += (seg[b * T_ + tt] != 0) ? 1 : 0;
    int pos = max(c - 1, 0) + CUR;

    if (tid < 64) {
        float frac = (2.0f * tid) / (float)H_;
        float ts = expf(frac * logf(1000000.0f));
        float ang = (float)pos / ts;
        sc[tid][0] = sinf(ang);
        sc[tid][1] = cosf(ang);
    }
    for (int e = tid; e < 2048; e += 256) {
        float s = 0.f;
#pragma unroll
        for (int sp = 0; sp < SPLITS; ++sp)
            s += part[((size_t)sp * 128 + row) * 2048 + e];
        S[e] = s;
    }
    __syncthreads();

    // q: 12 heads x 64 pairs
    for (int e = tid; e < 768; e += 256) {
        int n = e >> 6, i = e & 63;
        float x1 = S[n * 128 + i] + bq[n * 128 + i];
        float x2 = S[n * 128 + i + 64] + bq[n * 128 + i + 64];
        float s = sc[i][0], co = sc[i][1];
        q_rope[(size_t)row * 1536 + n * 128 + i]      = x1 * co - x2 * s;
        q_rope[(size_t)row * 1536 + n * 128 + i + 64] = x2 * co + x1 * s;
    }
    // k: 2 heads x 64 pairs
    if (tid < 128) {
        int n = tid >> 6, i = tid & 63;
        float x1 = S[1536 + n * 128 + i] + bk[n * 128 + i];
        float x2 = S[1536 + n * 128 + i + 64] + bk[n * 128 + i + 64];
        float s = sc[i][0], co = sc[i][1];
        k_new[(size_t)row * 256 + n * 128 + i]      = x1 * co - x2 * s;
        k_new[(size_t)row * 256 + n * 128 + i + 64] = x2 * co + x1 * s;
    }
    // v: bias only
    v_new[(size_t)row * 256 + tid] = S[1792 + tid] + bv[tid];
}

// ---------------------------------------------------------------------------
// MFMA flash attention, split-KV (unchanged from round 2).
// ---------------------------------------------------------------------------
__global__ __launch_bounds__(384, 2) void attn_mfma(
    const float* __restrict__ q_rope, const float* __restrict__ k_new,
    const float* __restrict__ v_new,
    const float* __restrict__ k_cache, const float* __restrict__ v_cache,
    const int* __restrict__ seg, const int* __restrict__ start_ind,
    const int* __restrict__ curp,
    float* __restrict__ part)
{
    const int chunk = blockIdx.x, b = blockIdx.y, kh = blockIdx.z;
    const int tid = threadIdx.x;
    const int wave = tid >> 6, lane = tid & 63;
    const int col = lane & 15, g = lane >> 4;
    const float scale = 0.088388347648318447f;
    const float NEG_INF = -__builtin_inff();

    const int CUR = curp[0];
    const int SPAN = CUR + T_;
    const int CH = (SPAN + NCHUNK - 1) / NCHUNK;
    const int s0 = chunk * CH;
    const int s1 = min(s0 + CH, SPAN);

    int st = start_ind[b];
    if (st < 0) {
        st = 0;
        for (int tt = 0; tt < T_; ++tt)
            if (seg[b * T_ + tt] != 0) { st = tt; break; }
    }

    __shared__ __align__(16) unsigned short K_hi[32][136], K_lo[32][136];
    __shared__ __align__(16) unsigned short Vt_hi[128][40], Vt_lo[128][40];
    __shared__ __align__(16) unsigned short P_hi[6][16][40], P_lo[6][16][40];

    const int qbase = wave * 16;
    const int qi_a = qbase + col;
    const int t_a = (qi_a * 171) >> 10;
    const int gh_a = qi_a - t_a * G_;
    const float* qp = &q_rope[(((size_t)b * T_ + t_a) * N_ + kh * G_ + gh_a) * H_];
    bf16x8 qh[4], ql[4];
#pragma unroll
    for (int ks = 0; ks < 4; ++ks) {
        float4 va = *(const float4*)&qp[ks * 32 + g * 8];
        float4 vb = *(const float4*)&qp[ks * 32 + g * 8 + 4];
        float f[8] = {va.x, va.y, va.z, va.w, vb.x, vb.y, vb.z, vb.w};
#pragma unroll
        for (int i = 0; i < 8; ++i) {
            float xs = f[i] * scale;
            unsigned short hh = f2bf(xs);
            qh[ks][i] = (short)hh;
            ql[ks][i] = (short)f2bf(xs - bf2f(hh));
        }
    }

    int qpos_r[4], segid_r[4];
#pragma unroll
    for (int j = 0; j < 4; ++j) {
        int qi_c = qbase + g * 4 + j;
        int t_c = (qi_c * 171) >> 10;
        segid_r[j] = seg[b * T_ + t_c];
        qpos_r[j] = CUR + t_c - st;
    }

    float m[4], lsum[4];
#pragma unroll
    for (int j = 0; j < 4; ++j) { m[j] = NEG_INF; lsum[j] = 0.f; }
    f32x4 oacc[8];
#pragma unroll
    for (int nt = 0; nt < 8; ++nt) oacc[nt] = (f32x4){0.f, 0.f, 0.f, 0.f};

    for (int stile = s0; stile < s1; stile += 32) {
        __syncthreads();
        for (int c = tid; c < 1024; c += 384) {
            int key = c >> 5, d4 = c & 31;
            int s = stile + key;
            float4 v = {0.f, 0.f, 0.f, 0.f};
            if (s < s1) {
                const float* src = (s < CUR)
                    ? &k_cache[((((size_t)b * S_ + s) * KH_) + kh) * H_ + d4 * 4]
                    : &k_new[((((size_t)b * T_ + (s - CUR)) * KH_) + kh) * H_ + d4 * 4];
                v = *(const float4*)src;
            }
            float f[4] = {v.x, v.y, v.z, v.w};
            u16x4 hv, lv;
#pragma unroll
            for (int i = 0; i < 4; ++i) {
                unsigned short hh = f2bf(f[i]);
                hv[i] = hh; lv[i] = f2bf(f[i] - bf2f(hh));
            }
            *(u16x4*)&K_hi[key][d4 * 4] = hv;
            *(u16x4*)&K_lo[key][d4 * 4] = lv;
        }
        if (tid < 256) {
            int ky4 = tid >> 5, d4 = tid & 31;
            float a[4][4];
#pragma unroll
            for (int r = 0; r < 4; ++r) {
                int s = stile + ky4 * 4 + r;
                float4 v = {0.f, 0.f, 0.f, 0.f};
                if (s < s1) {
                    const float* src = (s < CUR)
                        ? &v_cache[((((size_t)b * S_ + s) * KH_) + kh) * H_ + d4 * 4]
                        : &v_new[((((size_t)b * T_ + (s - CUR)) * KH_) + kh) * H_ + d4 * 4];
                    v = *(const float4*)src;
                }
                a[r][0] = v.x; a[r][1] = v.y; a[r][2] = v.z; a[r][3] = v.w;
            }
#pragma unroll
            for (int dd = 0; dd < 4; ++dd) {
                u16x4 hv, lv;
#pragma unroll
                for (int r = 0; r < 4; ++r) {
                    unsigned short hh = f2bf(a[r][dd]);
                    hv[r] = hh; lv[r] = f2bf(a[r][dd] - bf2f(hh));
                }
                *(u16x4*)&Vt_hi[d4 * 4 + dd][ky4 * 4] = hv;
                *(u16x4*)&Vt_lo[d4 * 4 + dd][ky4 * 4] = lv;
            }
        }
        __syncthreads();

        f32x4 sacc0 = {0.f, 0.f, 0.f, 0.f}, sacc1 = {0.f, 0.f, 0.f, 0.f};
#pragma unroll
        for (int ks = 0; ks < 4; ++ks) {
            bf16x8 k0h = *(const bf16x8*)&K_hi[col][ks * 32 + g * 8];
            bf16x8 k0l = *(const bf16x8*)&K_lo[col][ks * 32 + g * 8];
            bf16x8 k1h = *(const bf16x8*)&K_hi[16 + col][ks * 32 + g * 8];
            bf16x8 k1l = *(const bf16x8*)&K_lo[16 + col][ks * 32 + g * 8];
            sacc0 = __builtin_amdgcn_mfma_f32_16x16x32_bf16(qh[ks], k0h, sacc0, 0, 0, 0);
            sacc0 = __builtin_amdgcn_mfma_f32_16x16x32_bf16(qh[ks], k0l, sacc0, 0, 0, 0);
            sacc0 = __builtin_amdgcn_mfma_f32_16x16x32_bf16(ql[ks], k0h, sacc0, 0, 0, 0);
            sacc1 = __builtin_amdgcn_mfma_f32_16x16x32_bf16(qh[ks], k1h, sacc1, 0, 0, 0);
            sacc1 = __builtin_amdgcn_mfma_f32_16x16x32_bf16(qh[ks], k1l, sacc1, 0, 0, 0);
            sacc1 = __builtin_amdgcn_mfma_f32_16x16x32_bf16(ql[ks], k1h, sacc1, 0, 0, 0);
        }

        float rj[4];
        const int skey0 = stile + col, skey1 = stile + 16 + col;
#pragma unroll
        for (int j = 0; j < 4; ++j) {
            bool v0 = (skey0 < s1) && (skey0 - st <= qpos_r[j]) &&
                      (((skey0 >= st) ? 1 : 0) == segid_r[j]);
            bool v1 = (skey1 < s1) && (skey1 - st <= qpos_r[j]) &&
                      (((skey1 >= st) ? 1 : 0) == segid_r[j]);
            float lg0 = v0 ? sacc0[j] : NEG_INF;
            float lg1 = v1 ? sacc1[j] : NEG_INF;
            float tm = fmaxf(lg0, lg1);
            tm = fmaxf(tm, __shfl_xor(tm, 1));
            tm = fmaxf(tm, __shfl_xor(tm, 2));
            tm = fmaxf(tm, __shfl_xor(tm, 4));
            tm = fmaxf(tm, __shfl_xor(tm, 8));
            float mn = fmaxf(m[j], tm);
            float r, p0, p1;
            if (mn == NEG_INF) { r = 1.f; p0 = 0.f; p1 = 0.f; }
            else {
                r  = __expf(m[j] - mn);
                p0 = __expf(lg0 - mn);
                p1 = __expf(lg1 - mn);
            }
            float ps = p0 + p1;
            ps += __shfl_xor(ps, 1);
            ps += __shfl_xor(ps, 2);
            ps += __shfl_xor(ps, 4);
            ps += __shfl_xor(ps, 8);
            lsum[j] = lsum[j] * r + ps;
            m[j] = mn;
            rj[j] = r;
            int row = g * 4 + j;
            unsigned short h0 = f2bf(p0);
            P_hi[wave][row][col] = h0;
            P_lo[wave][row][col] = f2bf(p0 - bf2f(h0));
            unsigned short h1 = f2bf(p1);
            P_hi[wave][row][16 + col] = h1;
            P_lo[wave][row][16 + col] = f2bf(p1 - bf2f(h1));
        }

#pragma unroll
        for (int nt = 0; nt < 8; ++nt) {
#pragma unroll
            for (int j = 0; j < 4; ++j) oacc[nt][j] *= rj[j];
        }

        bf16x8 pah = *(const bf16x8*)&P_hi[wave][col][g * 8];
        bf16x8 pal = *(const bf16x8*)&P_lo[wave][col][g * 8];
#pragma unroll
        for (int nt = 0; nt < 8; ++nt) {
            bf16x8 vbh = *(const bf16x8*)&Vt_hi[nt * 16 + col][g * 8];
            bf16x8 vbl = *(const bf16x8*)&Vt_lo[nt * 16 + col][g * 8];
            oacc[nt] = __builtin_amdgcn_mfma_f32_16x16x32_bf16(pah, vbh, oacc[nt], 0, 0, 0);
            oacc[nt] = __builtin_amdgcn_mfma_f32_16x16x32_bf16(pah, vbl, oacc[nt], 0, 0, 0);
            oacc[nt] = __builtin_amdgcn_mfma_f32_16x16x32_bf16(pal, vbh, oacc[nt], 0, 0, 0);
        }
    }

    const size_t base_q = (((size_t)chunk * B_ + b) * KH_ + kh) * 96;
#pragma unroll
    for (int j = 0; j < 4; ++j) {
        int qi = qbase + g * 4 + j;
        size_t pb = (base_q + qi) * 132;
        if (col == 0) { part[pb] = m[j]; part[pb + 1] = lsum[j]; }
#pragma unroll
        for (int nt = 0; nt < 8; ++nt)
            part[pb + 2 + nt * 16 + col] = oacc[nt][j];
    }
}

// ---------------------------------------------------------------------------
// Combine per-chunk partials -> qkv (b,t,N,H)
// ---------------------------------------------------------------------------
__global__ __launch_bounds__(256) void combine_kernel(
    const float* __restrict__ part, float* __restrict__ qkv)
{
    const int row = blockIdx.x;
    const int b = row >> 4, t = row & 15;
    const int tid = threadIdx.x;
    const int half = tid >> 7, h = tid & 127;
    const size_t cstride = (size_t)B_ * KH_ * 96 * 132;

    for (int nb = 0; nb < N_; nb += 2) {
        int n = nb + half;
        int kh = n / G_, g = n - kh * G_;
        int qi = t * G_ + g;
        size_t base0 = (((size_t)b * KH_ + kh) * 96 + qi) * 132;
        float M = -__builtin_inff();
        for (int c = 0; c < NCHUNK; ++c)
            M = fmaxf(M, part[base0 + c * cstride]);
        float den = 0.f, num = 0.f;
        for (int c = 0; c < NCHUNK; ++c) {
            float mc = part[base0 + c * cstride];
            float e = (M == -__builtin_inff() || mc == -__builtin_inff())
                          ? 0.f : expf(mc - M);
            den += e * part[base0 + c * cstride + 1];
            num += e * part[base0 + c * cstride + 2 + h];
        }
        qkv[(size_t)row * (N_ * H_) + n * H_ + h] = (den > 0.f) ? num / den : 0.f;
    }
}

// ---------------------------------------------------------------------------
// out[i] = sum over SPLITS partial planes
// ---------------------------------------------------------------------------
__global__ __launch_bounds__(256) void sum_reduce(
    const float* __restrict__ part, float* __restrict__ out, int n)
{
    int i = blockIdx.x * 256 + threadIdx.x;
    if (i < n) {
        float s = 0.f;
#pragma unroll
        for (int sp = 0; sp < SPLITS; ++sp) s += part[(size_t)sp * n + i];
        out[i] = s;
    }
}

// ---------------------------------------------------------------------------
extern "C" void kernel_launch(void* const* d_in, const int* in_sizes, int n_in,
                              void* d_out, int out_size, void* d_ws, size_t ws_size,
                              hipStream_t stream)
{
    (void)in_sizes; (void)n_in; (void)out_size; (void)ws_size;
    const float* x       = (const float*)d_in[0];
    const float* k_cache = (const float*)d_in[1];
    const float* v_cache = (const float*)d_in[2];
    const float* wq      = (const float*)d_in[3];
    const float* bq      = (const float*)d_in[4];
    const float* wk      = (const float*)d_in[5];
    const float* bk      = (const float*)d_in[6];
    const float* wv      = (const float*)d_in[7];
    const float* bv      = (const float*)d_in[8];
    const float* wo      = (const float*)d_in[9];
    const int*   seg     = (const int*)d_in[10];
    const int*   start_i = (const int*)d_in[11];
    const int*   curp    = (const int*)d_in[12];
    float* out = (float*)d_out;
    float* ws  = (float*)d_ws;

    const size_t PQKV = (size_t)SPLITS * 128 * 2048;          // 2,097,152 (reused for out partials)
    const size_t QSZ  = (size_t)B_ * T_ * N_ * H_;            // 196,608
    const size_t KSZ  = (size_t)B_ * T_ * KH_ * H_;           // 32,768
    float* partP  = ws;
    float* q_rope = partP + PQKV;
    float* k_new  = q_rope + QSZ;
    float* v_new  = k_new + KSZ;
    float* partA  = v_new + KSZ;
    const size_t PSZ = (size_t)NCHUNK * B_ * KH_ * 96 * 132;  // 3,244,032
    float* qkv    = partA + PSZ;

    // fused q/k/v projection, split-K partials
    gemm_splitk<<<dim3(32, 2, SPLITS), 256, 0, stream>>>(
        x, wq, 1536, 1536, wk, 256, 256, wv, 256, partP, 2048, D_);

    rope_reduce<<<B_ * T_, 256, 0, stream>>>(partP, bq, bk, bv, seg, curp,
                                             q_rope, k_new, v_new);

    attn_mfma<<<dim3(NCHUNK, B_, KH_), 384, 0, stream>>>(
        q_rope, k_new, v_new, k_cache, v_cache, seg, start_i, curp, partA);

    combine_kernel<<<B_ * T_, 256, 0, stream>>>(partA, qkv);

    // output projection, split-K partials (reuses partP)
    gemm_splitk<<<dim3(24, 2, SPLITS), 256, 0, stream>>>(
        qkv, wo, 1536, 1536, wo, 0, 1536, wo, 1536, partP, 1536, N_ * H_);

    sum_reduce<<<(B_ * T_ * D_ + 255) / 256, 256, 0, stream>>>(
        partP, out, B_ * T_ * D_);
}

// Round 4
// 95.230 us; speedup vs baseline: 4.6472x; 1.1301x over previous
//
#include <hip/hip_runtime.h>

#define B_ 8
#define T_ 16
#define D_ 1536
#define N_ 12
#define KH_ 2
#define G_ 6
#define H_ 128
#define S_ 8192
#define NCHUNK 16
#define SPLITS 8

typedef __attribute__((ext_vector_type(8))) short bf16x8;
typedef __attribute__((ext_vector_type(4))) float f32x4;
typedef __attribute__((ext_vector_type(4))) unsigned short u16x4;

__device__ __forceinline__ unsigned short f2bf(float x) {
    unsigned u = __float_as_uint(x);
    u += 0x7fffu + ((u >> 16) & 1u);
    return (unsigned short)(u >> 16);
}
__device__ __forceinline__ float bf2f(unsigned short h) {
    return __uint_as_float(((unsigned)h) << 16);
}

// ---------------------------------------------------------------------------
// Split-K MFMA GEMM with split-bf16 (3-product) accuracy. (unchanged)
// ---------------------------------------------------------------------------
__global__ __launch_bounds__(256, 4) void gemm_splitk(
    const float* __restrict__ A,
    const float* __restrict__ W0, int n0, int ldb0,
    const float* __restrict__ W1, int n1, int ldb1,
    const float* __restrict__ W2, int ldb2,
    float* __restrict__ part, int NTOT, int Kdim)
{
    __shared__ __align__(16) unsigned short Ah[64][40], Al[64][40];
    __shared__ __align__(16) unsigned short Bh[64][40], Bl[64][40];
    const int tid = threadIdx.x;
    const int wave = tid >> 6, lane = tid & 63;
    const int col = lane & 15, g = lane >> 4;
    const int row0 = blockIdx.y * 64;
    const int c0 = blockIdx.x * 64;
    const int ks = Kdim / gridDim.z;
    const int k0 = blockIdx.z * ks;

    const float* Bp; int ldb, bc0;
    if (c0 < n0)           { Bp = W0; ldb = ldb0; bc0 = c0; }
    else if (c0 < n0 + n1) { Bp = W1; ldb = ldb1; bc0 = c0 - n0; }
    else                   { Bp = W2; ldb = ldb2; bc0 = c0 - n0 - n1; }

    f32x4 acc[4];
#pragma unroll
    for (int nt = 0; nt < 4; ++nt) acc[nt] = (f32x4){0.f, 0.f, 0.f, 0.f};

    for (int kk = 0; kk < ks; kk += 32) {
        __syncthreads();
        if (tid < 128) {
#pragma unroll
            for (int c = tid; c < 512; c += 128) {
                int r = c >> 3, k4 = c & 7;
                float4 v = *(const float4*)&A[(size_t)(row0 + r) * Kdim + k0 + kk + k4 * 4];
                float f[4] = {v.x, v.y, v.z, v.w};
                u16x4 hv, lv;
#pragma unroll
                for (int i = 0; i < 4; ++i) {
                    unsigned short hh = f2bf(f[i]);
                    hv[i] = hh; lv[i] = f2bf(f[i] - bf2f(hh));
                }
                *(u16x4*)&Ah[r][k4 * 4] = hv;
                *(u16x4*)&Al[r][k4 * 4] = lv;
            }
        } else {
            int t2 = tid - 128;
            int kq = t2 >> 4, cq = t2 & 15;
            float a[4][4];
#pragma unroll
            for (int r = 0; r < 4; ++r) {
                float4 v = *(const float4*)&Bp[(size_t)(k0 + kk + kq * 4 + r) * ldb + bc0 + cq * 4];
                a[r][0] = v.x; a[r][1] = v.y; a[r][2] = v.z; a[r][3] = v.w;
            }
#pragma unroll
            for (int cc = 0; cc < 4; ++cc) {
                u16x4 hv, lv;
#pragma unroll
                for (int r = 0; r < 4; ++r) {
                    unsigned short hh = f2bf(a[r][cc]);
                    hv[r] = hh; lv[r] = f2bf(a[r][cc] - bf2f(hh));
                }
                *(u16x4*)&Bh[cq * 4 + cc][kq * 4] = hv;
                *(u16x4*)&Bl[cq * 4 + cc][kq * 4] = lv;
            }
        }
        __syncthreads();

        bf16x8 ah = *(const bf16x8*)&Ah[wave * 16 + col][g * 8];
        bf16x8 al = *(const bf16x8*)&Al[wave * 16 + col][g * 8];
#pragma unroll
        for (int nt = 0; nt < 4; ++nt) {
            bf16x8 bh = *(const bf16x8*)&Bh[nt * 16 + col][g * 8];
            bf16x8 bl = *(const bf16x8*)&Bl[nt * 16 + col][g * 8];
            acc[nt] = __builtin_amdgcn_mfma_f32_16x16x32_bf16(ah, bh, acc[nt], 0, 0, 0);
            acc[nt] = __builtin_amdgcn_mfma_f32_16x16x32_bf16(ah, bl, acc[nt], 0, 0, 0);
            acc[nt] = __builtin_amdgcn_mfma_f32_16x16x32_bf16(al, bh, acc[nt], 0, 0, 0);
        }
    }
#pragma unroll
    for (int nt = 0; nt < 4; ++nt)
#pragma unroll
        for (int j = 0; j < 4; ++j) {
            size_t prow = (size_t)blockIdx.z * 128 + row0 + wave * 16 + g * 4 + j;
            part[prow * NTOT + c0 + nt * 16 + col] = acc[nt][j];
        }
}

// ---------------------------------------------------------------------------
// Reduce SPLITS partials + bias + RoPE. (unchanged)
// ---------------------------------------------------------------------------
__global__ __launch_bounds__(256) void rope_reduce(
    const float* __restrict__ part,
    const float* __restrict__ bq, const float* __restrict__ bk,
    const float* __restrict__ bv,
    const int* __restrict__ seg, const int* __restrict__ curp,
    float* __restrict__ q_rope, float* __restrict__ k_new,
    float* __restrict__ v_new)
{
    const int row = blockIdx.x;
    const int b = row >> 4, t = row & 15;
    const int tid = threadIdx.x;
    __shared__ float S[2048];
    __shared__ float sc[64][2];

    const int CUR = curp[0];
    int c = 0;
    for (int tt = 0; tt <= t; ++tt) c += (seg[b * T_ + tt] != 0) ? 1 : 0;
    int pos = max(c - 1, 0) + CUR;

    if (tid < 64) {
        float frac = (2.0f * tid) / (float)H_;
        float ts = expf(frac * logf(1000000.0f));
        float ang = (float)pos / ts;
        sc[tid][0] = sinf(ang);
        sc[tid][1] = cosf(ang);
    }
    for (int e = tid; e < 2048; e += 256) {
        float s = 0.f;
#pragma unroll
        for (int sp = 0; sp < SPLITS; ++sp)
            s += part[((size_t)sp * 128 + row) * 2048 + e];
        S[e] = s;
    }
    __syncthreads();

    for (int e = tid; e < 768; e += 256) {
        int n = e >> 6, i = e & 63;
        float x1 = S[n * 128 + i] + bq[n * 128 + i];
        float x2 = S[n * 128 + i + 64] + bq[n * 128 + i + 64];
        float s = sc[i][0], co = sc[i][1];
        q_rope[(size_t)row * 1536 + n * 128 + i]      = x1 * co - x2 * s;
        q_rope[(size_t)row * 1536 + n * 128 + i + 64] = x2 * co + x1 * s;
    }
    if (tid < 128) {
        int n = tid >> 6, i = tid & 63;
        float x1 = S[1536 + n * 128 + i] + bk[n * 128 + i];
        float x2 = S[1536 + n * 128 + i + 64] + bk[n * 128 + i + 64];
        float s = sc[i][0], co = sc[i][1];
        k_new[(size_t)row * 256 + n * 128 + i]      = x1 * co - x2 * s;
        k_new[(size_t)row * 256 + n * 128 + i + 64] = x2 * co + x1 * s;
    }
    v_new[(size_t)row * 256 + tid] = S[1792 + tid] + bv[tid];
}

// ---------------------------------------------------------------------------
// MFMA flash attention with 2-deep register-staged pipeline (T14).
// grid = (NCHUNK, B, KH), 384 thr = 6 waves, wave owns 16 queries.
// Pipeline: issue loads for tile t+2 into regs right after tile t's
// convert-barrier, so HBM latency hides under tile t compute + t+1 convert.
// ---------------------------------------------------------------------------
__global__ __launch_bounds__(384, 2) void attn_mfma(
    const float* __restrict__ q_rope, const float* __restrict__ k_new,
    const float* __restrict__ v_new,
    const float* __restrict__ k_cache, const float* __restrict__ v_cache,
    const int* __restrict__ seg, const int* __restrict__ start_ind,
    const int* __restrict__ curp,
    float* __restrict__ part)
{
    const int chunk = blockIdx.x, b = blockIdx.y, kh = blockIdx.z;
    const int tid = threadIdx.x;
    const int wave = tid >> 6, lane = tid & 63;
    const int col = lane & 15, g = lane >> 4;
    const float scale = 0.088388347648318447f;
    const float NEG_INF = -__builtin_inff();

    const int CUR = curp[0];
    const int SPAN = CUR + T_;
    const int CH = (SPAN + NCHUNK - 1) / NCHUNK;
    const int s0 = chunk * CH;
    const int s1 = min(s0 + CH, SPAN);

    int st = start_ind[b];
    if (st < 0) {
        st = 0;
        for (int tt = 0; tt < T_; ++tt)
            if (seg[b * T_ + tt] != 0) { st = tt; break; }
    }

    __shared__ __align__(16) unsigned short K_hi[32][136], K_lo[32][136];
    __shared__ __align__(16) unsigned short Vt_hi[128][40], Vt_lo[128][40];
    __shared__ __align__(16) unsigned short P_hi[6][16][40], P_lo[6][16][40];

    // ---- Q prologue ----
    const int qbase = wave * 16;
    const int qi_a = qbase + col;
    const int t_a = (qi_a * 171) >> 10;
    const int gh_a = qi_a - t_a * G_;
    const float* qp = &q_rope[(((size_t)b * T_ + t_a) * N_ + kh * G_ + gh_a) * H_];
    bf16x8 qh[4], ql[4];
#pragma unroll
    for (int ks = 0; ks < 4; ++ks) {
        float4 va = *(const float4*)&qp[ks * 32 + g * 8];
        float4 vb = *(const float4*)&qp[ks * 32 + g * 8 + 4];
        float f[8] = {va.x, va.y, va.z, va.w, vb.x, vb.y, vb.z, vb.w};
#pragma unroll
        for (int i = 0; i < 8; ++i) {
            float xs = f[i] * scale;
            unsigned short hh = f2bf(xs);
            qh[ks][i] = (short)hh;
            ql[ks][i] = (short)f2bf(xs - bf2f(hh));
        }
    }

    int qpos_r[4], segid_r[4];
#pragma unroll
    for (int j = 0; j < 4; ++j) {
        int qi_c = qbase + g * 4 + j;
        int t_c = (qi_c * 171) >> 10;
        segid_r[j] = seg[b * T_ + t_c];
        qpos_r[j] = CUR + t_c - st;
    }

    float m[4], lsum[4];
#pragma unroll
    for (int j = 0; j < 4; ++j) { m[j] = NEG_INF; lsum[j] = 0.f; }
    f32x4 oacc[8];
#pragma unroll
    for (int nt = 0; nt < 8; ++nt) oacc[nt] = (f32x4){0.f, 0.f, 0.f, 0.f};

    // ---- register staging helpers (all indices compile-time, rule #20) ----
    const int vky4 = tid >> 5, vd4 = tid & 31;   // V-assignment (tid<256)

    auto issueK = [&](float4* kreg, int stile) {
#pragma unroll
        for (int i = 0; i < 3; ++i) {
            int c = tid + i * 384;
            float4 v = {0.f, 0.f, 0.f, 0.f};
            if (c < 1024) {
                int key = c >> 5, d4 = c & 31;
                int s = stile + key;
                if (s < s1) {
                    const float* src = (s < CUR)
                        ? &k_cache[((((size_t)b * S_ + s) * KH_) + kh) * H_ + d4 * 4]
                        : &k_new[((((size_t)b * T_ + (s - CUR)) * KH_) + kh) * H_ + d4 * 4];
                    v = *(const float4*)src;
                }
            }
            kreg[i] = v;
        }
    };
    auto issueV = [&](float4* vreg, int stile) {
        if (tid < 256) {
#pragma unroll
            for (int r = 0; r < 4; ++r) {
                int s = stile + vky4 * 4 + r;
                float4 v = {0.f, 0.f, 0.f, 0.f};
                if (s < s1) {
                    const float* src = (s < CUR)
                        ? &v_cache[((((size_t)b * S_ + s) * KH_) + kh) * H_ + vd4 * 4]
                        : &v_new[((((size_t)b * T_ + (s - CUR)) * KH_) + kh) * H_ + vd4 * 4];
                    v = *(const float4*)src;
                }
                vreg[r] = v;
            }
        }
    };
    auto convertKV = [&](const float4* kreg, const float4* vreg) {
#pragma unroll
        for (int i = 0; i < 3; ++i) {
            int c = tid + i * 384;
            if (c < 1024) {
                int key = c >> 5, d4 = c & 31;
                float f[4] = {kreg[i].x, kreg[i].y, kreg[i].z, kreg[i].w};
                u16x4 hv, lv;
#pragma unroll
                for (int q = 0; q < 4; ++q) {
                    unsigned short hh = f2bf(f[q]);
                    hv[q] = hh; lv[q] = f2bf(f[q] - bf2f(hh));
                }
                *(u16x4*)&K_hi[key][d4 * 4] = hv;
                *(u16x4*)&K_lo[key][d4 * 4] = lv;
            }
        }
        if (tid < 256) {
            float a[4][4];
#pragma unroll
            for (int r = 0; r < 4; ++r) {
                a[r][0] = vreg[r].x; a[r][1] = vreg[r].y;
                a[r][2] = vreg[r].z; a[r][3] = vreg[r].w;
            }
#pragma unroll
            for (int dd = 0; dd < 4; ++dd) {
                u16x4 hv, lv;
#pragma unroll
                for (int r = 0; r < 4; ++r) {
                    unsigned short hh = f2bf(a[r][dd]);
                    hv[r] = hh; lv[r] = f2bf(a[r][dd] - bf2f(hh));
                }
                *(u16x4*)&Vt_hi[vd4 * 4 + dd][vky4 * 4] = hv;
                *(u16x4*)&Vt_lo[vd4 * 4 + dd][vky4 * 4] = lv;
            }
        }
    };

    auto computeTile = [&](int stile) {
        const bool full = (s1 - stile) > 16;
        f32x4 sacc0 = {0.f, 0.f, 0.f, 0.f}, sacc1 = {0.f, 0.f, 0.f, 0.f};
#pragma unroll
        for (int ks = 0; ks < 4; ++ks) {
            bf16x8 k0h = *(const bf16x8*)&K_hi[col][ks * 32 + g * 8];
            bf16x8 k0l = *(const bf16x8*)&K_lo[col][ks * 32 + g * 8];
            sacc0 = __builtin_amdgcn_mfma_f32_16x16x32_bf16(qh[ks], k0h, sacc0, 0, 0, 0);
            sacc0 = __builtin_amdgcn_mfma_f32_16x16x32_bf16(qh[ks], k0l, sacc0, 0, 0, 0);
            sacc0 = __builtin_amdgcn_mfma_f32_16x16x32_bf16(ql[ks], k0h, sacc0, 0, 0, 0);
        }
        if (full) {
#pragma unroll
            for (int ks = 0; ks < 4; ++ks) {
                bf16x8 k1h = *(const bf16x8*)&K_hi[16 + col][ks * 32 + g * 8];
                bf16x8 k1l = *(const bf16x8*)&K_lo[16 + col][ks * 32 + g * 8];
                sacc1 = __builtin_amdgcn_mfma_f32_16x16x32_bf16(qh[ks], k1h, sacc1, 0, 0, 0);
                sacc1 = __builtin_amdgcn_mfma_f32_16x16x32_bf16(qh[ks], k1l, sacc1, 0, 0, 0);
                sacc1 = __builtin_amdgcn_mfma_f32_16x16x32_bf16(ql[ks], k1h, sacc1, 0, 0, 0);
            }
        }

        float rj[4];
        const int skey0 = stile + col, skey1 = stile + 16 + col;
#pragma unroll
        for (int j = 0; j < 4; ++j) {
            bool v0 = (skey0 < s1) && (skey0 - st <= qpos_r[j]) &&
                      (((skey0 >= st) ? 1 : 0) == segid_r[j]);
            bool v1 = (skey1 < s1) && (skey1 - st <= qpos_r[j]) &&
                      (((skey1 >= st) ? 1 : 0) == segid_r[j]);
            float lg0 = v0 ? sacc0[j] : NEG_INF;
            float lg1 = v1 ? sacc1[j] : NEG_INF;
            float tm = fmaxf(lg0, lg1);
            tm = fmaxf(tm, __shfl_xor(tm, 1));
            tm = fmaxf(tm, __shfl_xor(tm, 2));
            tm = fmaxf(tm, __shfl_xor(tm, 4));
            tm = fmaxf(tm, __shfl_xor(tm, 8));
            float mn = fmaxf(m[j], tm);
            float r, p0, p1;
            if (mn == NEG_INF) { r = 1.f; p0 = 0.f; p1 = 0.f; }
            else {
                r  = __expf(m[j] - mn);
                p0 = __expf(lg0 - mn);
                p1 = __expf(lg1 - mn);
            }
            float ps = p0 + p1;
            ps += __shfl_xor(ps, 1);
            ps += __shfl_xor(ps, 2);
            ps += __shfl_xor(ps, 4);
            ps += __shfl_xor(ps, 8);
            lsum[j] = lsum[j] * r + ps;
            m[j] = mn;
            rj[j] = r;
            int row = g * 4 + j;
            unsigned short h0 = f2bf(p0);
            P_hi[wave][row][col] = h0;
            P_lo[wave][row][col] = f2bf(p0 - bf2f(h0));
            unsigned short h1 = f2bf(p1);
            P_hi[wave][row][16 + col] = h1;
            P_lo[wave][row][16 + col] = f2bf(p1 - bf2f(h1));
        }

#pragma unroll
        for (int nt = 0; nt < 8; ++nt) {
#pragma unroll
            for (int j = 0; j < 4; ++j) oacc[nt][j] *= rj[j];
        }

        bf16x8 pah = *(const bf16x8*)&P_hi[wave][col][g * 8];
        bf16x8 pal = *(const bf16x8*)&P_lo[wave][col][g * 8];
#pragma unroll
        for (int nt = 0; nt < 8; ++nt) {
            bf16x8 vbh = *(const bf16x8*)&Vt_hi[nt * 16 + col][g * 8];
            bf16x8 vbl = *(const bf16x8*)&Vt_lo[nt * 16 + col][g * 8];
            oacc[nt] = __builtin_amdgcn_mfma_f32_16x16x32_bf16(pah, vbh, oacc[nt], 0, 0, 0);
            oacc[nt] = __builtin_amdgcn_mfma_f32_16x16x32_bf16(pah, vbl, oacc[nt], 0, 0, 0);
            oacc[nt] = __builtin_amdgcn_mfma_f32_16x16x32_bf16(pal, vbh, oacc[nt], 0, 0, 0);
        }
    };

    // ---- 2-deep pipelined main loop (A/B register buffers, static names) --
    const int ntiles = (s1 - s0 + 31) >> 5;
    float4 kregA[3], vregA[4], kregB[3], vregB[4];

    issueK(kregA, s0); issueV(vregA, s0);
    if (ntiles > 1) { issueK(kregB, s0 + 32); issueV(vregB, s0 + 32); }

    for (int ti = 0; ti < ntiles; ti += 2) {
        // phase A
        {
            convertKV(kregA, vregA);
            __syncthreads();
            if (ti + 2 < ntiles) {
                issueK(kregA, s0 + (ti + 2) * 32);
                issueV(vregA, s0 + (ti + 2) * 32);
            }
            computeTile(s0 + ti * 32);
            __syncthreads();
        }
        // phase B
        if (ti + 1 < ntiles) {
            convertKV(kregB, vregB);
            __syncthreads();
            if (ti + 3 < ntiles) {
                issueK(kregB, s0 + (ti + 3) * 32);
                issueV(vregB, s0 + (ti + 3) * 32);
            }
            computeTile(s0 + (ti + 1) * 32);
            __syncthreads();
        }
    }

    // ---- write partials ----
    const size_t base_q = (((size_t)chunk * B_ + b) * KH_ + kh) * 96;
#pragma unroll
    for (int j = 0; j < 4; ++j) {
        int qi = qbase + g * 4 + j;
        size_t pb = (base_q + qi) * 132;
        if (col == 0) { part[pb] = m[j]; part[pb + 1] = lsum[j]; }
#pragma unroll
        for (int nt = 0; nt < 8; ++nt)
            part[pb + 2 + nt * 16 + col] = oacc[nt][j];
    }
}

// ---------------------------------------------------------------------------
// Combine per-chunk partials -> qkv (b,t,N,H) (unchanged)
// ---------------------------------------------------------------------------
__global__ __launch_bounds__(256) void combine_kernel(
    const float* __restrict__ part, float* __restrict__ qkv)
{
    const int row = blockIdx.x;
    const int b = row >> 4, t = row & 15;
    const int tid = threadIdx.x;
    const int half = tid >> 7, h = tid & 127;
    const size_t cstride = (size_t)B_ * KH_ * 96 * 132;

    for (int nb = 0; nb < N_; nb += 2) {
        int n = nb + half;
        int kh = n / G_, g = n - kh * G_;
        int qi = t * G_ + g;
        size_t base0 = (((size_t)b * KH_ + kh) * 96 + qi) * 132;
        float M = -__builtin_inff();
        for (int c = 0; c < NCHUNK; ++c)
            M = fmaxf(M, part[base0 + c * cstride]);
        float den = 0.f, num = 0.f;
        for (int c = 0; c < NCHUNK; ++c) {
            float mc = part[base0 + c * cstride];
            float e = (M == -__builtin_inff() || mc == -__builtin_inff())
                          ? 0.f : expf(mc - M);
            den += e * part[base0 + c * cstride + 1];
            num += e * part[base0 + c * cstride + 2 + h];
        }
        qkv[(size_t)row * (N_ * H_) + n * H_ + h] = (den > 0.f) ? num / den : 0.f;
    }
}

// ---------------------------------------------------------------------------
__global__ __launch_bounds__(256) void sum_reduce(
    const float* __restrict__ part, float* __restrict__ out, int n)
{
    int i = blockIdx.x * 256 + threadIdx.x;
    if (i < n) {
        float s = 0.f;
#pragma unroll
        for (int sp = 0; sp < SPLITS; ++sp) s += part[(size_t)sp * n + i];
        out[i] = s;
    }
}

// ---------------------------------------------------------------------------
extern "C" void kernel_launch(void* const* d_in, const int* in_sizes, int n_in,
                              void* d_out, int out_size, void* d_ws, size_t ws_size,
                              hipStream_t stream)
{
    (void)in_sizes; (void)n_in; (void)out_size; (void)ws_size;
    const float* x       = (const float*)d_in[0];
    const float* k_cache = (const float*)d_in[1];
    const float* v_cache = (const float*)d_in[2];
    const float* wq      = (const float*)d_in[3];
    const float* bq      = (const float*)d_in[4];
    const float* wk      = (const float*)d_in[5];
    const float* bk      = (const float*)d_in[6];
    const float* wv      = (const float*)d_in[7];
    const float* bv      = (const float*)d_in[8];
    const float* wo      = (const float*)d_in[9];
    const int*   seg     = (const int*)d_in[10];
    const int*   start_i = (const int*)d_in[11];
    const int*   curp    = (const int*)d_in[12];
    float* out = (float*)d_out;
    float* ws  = (float*)d_ws;

    const size_t PQKV = (size_t)SPLITS * 128 * 2048;
    const size_t QSZ  = (size_t)B_ * T_ * N_ * H_;
    const size_t KSZ  = (size_t)B_ * T_ * KH_ * H_;
    float* partP  = ws;
    float* q_rope = partP + PQKV;
    float* k_new  = q_rope + QSZ;
    float* v_new  = k_new + KSZ;
    float* partA  = v_new + KSZ;
    const size_t PSZ = (size_t)NCHUNK * B_ * KH_ * 96 * 132;
    float* qkv    = partA + PSZ;

    gemm_splitk<<<dim3(32, 2, SPLITS), 256, 0, stream>>>(
        x, wq, 1536, 1536, wk, 256, 256, wv, 256, partP, 2048, D_);

    rope_reduce<<<B_ * T_, 256, 0, stream>>>(partP, bq, bk, bv, seg, curp,
                                             q_rope, k_new, v_new);

    attn_mfma<<<dim3(NCHUNK, B_, KH_), 384, 0, stream>>>(
        q_rope, k_new, v_new, k_cache, v_cache, seg, start_i, curp, partA);

    combine_kernel<<<B_ * T_, 256, 0, stream>>>(partA, qkv);

    gemm_splitk<<<dim3(24, 2, SPLITS), 256, 0, stream>>>(
        qkv, wo, 1536, 1536, wo, 0, 1536, wo, 1536, partP, 1536, N_ * H_);

    sum_reduce<<<(B_ * T_ * D_ + 255) / 256, 256, 0, stream>>>(
        partP, out, B_ * T_ * D_);
}